// Round 6
// baseline (71.041 us; speedup 1.0000x reference)
//
#include <hip/hip_runtime.h>
#include <cmath>

#define D 64
#define M 64

typedef float f4 __attribute__((ext_vector_type(4)));

// One block per (n,h). 256 threads: tx = t&15 owns 4 consecutive m-columns
// (float4), ty = t>>4 owns 4 d-rows (d = ty + 16j). Each thread touches 16
// elements of each big tensor. All 12 big-stream loads are issued up front
// (max MLP). Cache partition across graph replays: Si+Pi (128MB) load
// cached -> stay resident in the 256MiB Infinity Cache; Mi loads are
// nontemporal (stream from HBM, never evict Si/Pi); all big stores
// nontemporal. rsqrt keeps the load->store chain short; 32-bit indexing.
__global__ __launch_bounds__(256) void raa_kernel(
    const float* __restrict__ q, const float* __restrict__ kk,
    const float* __restrict__ vv, const float* __restrict__ Si,
    const float* __restrict__ Zi, const float* __restrict__ Pi,
    const float* __restrict__ Mi, const int* __restrict__ tind,
    float* __restrict__ oV, float* __restrict__ oSi, float* __restrict__ oZi,
    float* __restrict__ oPi, float* __restrict__ oMi)
{
  const int nh = blockIdx.x;
  const int t  = threadIdx.x;
  const int base = nh * D;               // (n,h,d) vectors
  const int big  = nh * (D * M);         // (n,h,d,m) tensors (fits 32-bit)

  __shared__ float sQ[D];
  __shared__ float sK[D];
  __shared__ float sVv[M];
  __shared__ float sZ1;
  __shared__ float vred[4][16][4];

  // ---- scalar time-dependent constants (double, matches numpy f64 path) ----
  const int ti = tind[0] + 1;
  const double td = (double)ti;
  const double mu_t   = pow(0.9, td);
  const double beta_t = pow(0.999, td);
  const float c1     = (float)(1.0 / (1.0 - mu_t));   // (1-MU)/(STEP*(1-MU^t))
  const float inv_bc = (float)(1.0 / (1.0 - beta_t));
  const double rho  = 2.0 / (1.0 - 0.999) - 1.0;
  const double rhoi = rho - 2.0 * td * beta_t / (1.0 - beta_t);
  const bool  use_ri = (rhoi > 4.0);
  const float ri = use_ri
      ? (float)sqrt((rhoi - 4.0) * (rhoi - 2.0) * rho /
                    ((rho - 4.0) * (rho - 2.0) * rhoi))
      : 0.0f;
  const float muf   = 0.9f;
  const float stepf = 0.1f;
  const float betaf = 0.999f;
  const float ombf  = (float)(1.0 - 0.999);

  // ---- prologue: issue this thread's 12 big-stream loads FIRST (MLP) ----
  const int tx = t & 15;   // m-group: columns tx*4 .. tx*4+3
  const int ty = t >> 4;   // d-group: rows ty + 16j
  const int off0 = big + ty * M + tx * 4;
  f4 pi[4], mi[4], si[4];
#pragma unroll
  for (int j = 0; j < 4; ++j) {
    const int off = off0 + j * (16 * M);
    pi[j] = *(const f4*)&Pi[off];                              // cached
    si[j] = *(const f4*)&Si[off];                              // cached
    mi[j] = __builtin_nontemporal_load((const f4*)&Mi[off]);   // streamed
  }

  // ---- small per-(n,h) vectors: Q, K, Zi_new, value; Z scalar ----
  if (t < D) {  // exactly wave 0
    const float x = q[base + t];
    const float y = kk[base + t];
    const float Qv = x > 0.f ? x + 1.f : expf(x);  // elu(x)+1
    const float Kv = y > 0.f ? y + 1.f : expf(y);
    const float zn = Zi[base + t] + Kv;
    sQ[t] = Qv;
    sK[t] = Kv;
    sVv[t] = vv[base + t];
    oZi[base + t] = zn;
    // Z = 1 / (dot(Q, Zi_new) + eps) via wave64 butterfly
    float p = Qv * zn;
    p += __shfl_xor(p, 1);
    p += __shfl_xor(p, 2);
    p += __shfl_xor(p, 4);
    p += __shfl_xor(p, 8);
    p += __shfl_xor(p, 16);
    p += __shfl_xor(p, 32);
    if (t == 0) sZ1 = 1.0f / (p + 1e-6f);
  }
  __syncthreads();

  const f4 val4 = *(const f4*)&sVv[tx * 4];
  f4 acc = (f4)(0.f);

#pragma unroll
  for (int j = 0; j < 4; ++j) {
    const int d = ty + 16 * j;
    const int off = off0 + j * (16 * M);
    const float Kd = sK[d];
    const float Qd = sQ[d];

    f4 u  = Kd * val4;
    f4 pn = (muf * pi[j] - stepf * u) * c1;
    f4 mn = betaf * mi[j] + ombf * (u * u);
    // store pn/mn immediately — no dependence on the rsqrt chain
    __builtin_nontemporal_store(pn, (f4*)&oPi[off]);
    __builtin_nontemporal_store(mn, (f4*)&oMi[off]);

    f4 sn;
    if (use_ri) {
      sn.x = si[j].x - pn.x * ri * rsqrtf(mn.x * inv_bc + 1e-16f);
      sn.y = si[j].y - pn.y * ri * rsqrtf(mn.y * inv_bc + 1e-16f);
      sn.z = si[j].z - pn.z * ri * rsqrtf(mn.z * inv_bc + 1e-16f);
      sn.w = si[j].w - pn.w * ri * rsqrtf(mn.w * inv_bc + 1e-16f);
    } else {
      sn = si[j] - pn;
    }
    __builtin_nontemporal_store(sn, (f4*)&oSi[off]);

    acc += Qd * sn;
  }

  // ---- V reduction: sum over d (16 ty-threads per tx) ----
  acc.x += __shfl_xor(acc.x, 16); acc.x += __shfl_xor(acc.x, 32);
  acc.y += __shfl_xor(acc.y, 16); acc.y += __shfl_xor(acc.y, 32);
  acc.z += __shfl_xor(acc.z, 16); acc.z += __shfl_xor(acc.z, 32);
  acc.w += __shfl_xor(acc.w, 16); acc.w += __shfl_xor(acc.w, 32);

  const int wave = t >> 6;
  const int lane = t & 63;
  if (lane < 16) {
    vred[wave][lane][0] = acc.x;
    vred[wave][lane][1] = acc.y;
    vred[wave][lane][2] = acc.z;
    vred[wave][lane][3] = acc.w;
  }
  __syncthreads();

  if (t < M) {
    const int mtx = t >> 2, mc = t & 3;
    const float s = vred[0][mtx][mc] + vred[1][mtx][mc] +
                    vred[2][mtx][mc] + vred[3][mtx][mc];
    oV[nh * M + t] = sZ1 * s;
  }
}

extern "C" void kernel_launch(void* const* d_in, const int* in_sizes, int n_in,
                              void* d_out, int out_size, void* d_ws, size_t ws_size,
                              hipStream_t stream) {
  const float* q   = (const float*)d_in[0];
  const float* kk  = (const float*)d_in[1];
  const float* vv  = (const float*)d_in[2];
  const float* Si  = (const float*)d_in[3];
  const float* Zi  = (const float*)d_in[4];
  const float* Pi  = (const float*)d_in[5];
  const float* Mi  = (const float*)d_in[6];
  const int*  tind = (const int*)d_in[7];

  // Outputs concatenated in return order: V, Si, Zi, Pi, Mi
  float* out = (float*)d_out;
  float* oV  = out;
  float* oSi = oV  + in_sizes[2];  // V has N*H*M elements (== value size)
  float* oZi = oSi + in_sizes[3];  // Si
  float* oPi = oZi + in_sizes[4];  // Zi
  float* oMi = oPi + in_sizes[5];  // Pi

  const int NH = in_sizes[0] / D;  // 4096
  raa_kernel<<<NH, 256, 0, stream>>>(q, kk, vv, Si, Zi, Pi, Mi, tind,
                                     oV, oSi, oZi, oPi, oMi);
}

// Round 7
// 65.895 us; speedup vs baseline: 1.0781x; 1.0781x over previous
//
#include <hip/hip_runtime.h>
#include <cmath>

#define D 64
#define M 64

typedef float f4 __attribute__((ext_vector_type(4)));

// One block per (n,h). 256 threads: tx = t&15 owns 4 consecutive m-columns
// (float4), ty = t>>4 owns 4 d-rows (d = ty + 16j). Each thread touches 16
// elements of each big tensor. All 12 big-stream loads are issued up front
// (max MLP). Loads are CACHED (L3 absorbs ~half the re-reads across graph
// replays: 196MB input vs 256MB Infinity Cache shared with the write
// stream); stores are nontemporal so the write streams allocate as little
// as possible. rsqrt keeps the load->store chain short; 32-bit indexing.
// Measured best: 67.8 us, FETCH 100MB, WRITE 199MB (R5).
__global__ __launch_bounds__(256) void raa_kernel(
    const float* __restrict__ q, const float* __restrict__ kk,
    const float* __restrict__ vv, const float* __restrict__ Si,
    const float* __restrict__ Zi, const float* __restrict__ Pi,
    const float* __restrict__ Mi, const int* __restrict__ tind,
    float* __restrict__ oV, float* __restrict__ oSi, float* __restrict__ oZi,
    float* __restrict__ oPi, float* __restrict__ oMi)
{
  const int nh = blockIdx.x;
  const int t  = threadIdx.x;
  const int base = nh * D;               // (n,h,d) vectors
  const int big  = nh * (D * M);         // (n,h,d,m) tensors (fits 32-bit)

  __shared__ float sQ[D];
  __shared__ float sK[D];
  __shared__ float sVv[M];
  __shared__ float sZ1;
  __shared__ float vred[4][16][4];

  // ---- scalar time-dependent constants (double, matches numpy f64 path) ----
  const int ti = tind[0] + 1;
  const double td = (double)ti;
  const double mu_t   = pow(0.9, td);
  const double beta_t = pow(0.999, td);
  const float c1     = (float)(1.0 / (1.0 - mu_t));   // (1-MU)/(STEP*(1-MU^t))
  const float inv_bc = (float)(1.0 / (1.0 - beta_t));
  const double rho  = 2.0 / (1.0 - 0.999) - 1.0;
  const double rhoi = rho - 2.0 * td * beta_t / (1.0 - beta_t);
  const bool  use_ri = (rhoi > 4.0);
  const float ri = use_ri
      ? (float)sqrt((rhoi - 4.0) * (rhoi - 2.0) * rho /
                    ((rho - 4.0) * (rho - 2.0) * rhoi))
      : 0.0f;
  const float muf   = 0.9f;
  const float stepf = 0.1f;
  const float betaf = 0.999f;
  const float ombf  = (float)(1.0 - 0.999);

  // ---- prologue: issue this thread's 12 big-stream loads FIRST (MLP) ----
  const int tx = t & 15;   // m-group: columns tx*4 .. tx*4+3
  const int ty = t >> 4;   // d-group: rows ty + 16j
  const int off0 = big + ty * M + tx * 4;
  f4 pi[4], mi[4], si[4];
#pragma unroll
  for (int j = 0; j < 4; ++j) {
    const int off = off0 + j * (16 * M);
    pi[j] = *(const f4*)&Pi[off];
    mi[j] = *(const f4*)&Mi[off];
    si[j] = *(const f4*)&Si[off];
  }

  // ---- small per-(n,h) vectors: Q, K, Zi_new, value; Z scalar ----
  if (t < D) {  // exactly wave 0
    const float x = q[base + t];
    const float y = kk[base + t];
    const float Qv = x > 0.f ? x + 1.f : expf(x);  // elu(x)+1
    const float Kv = y > 0.f ? y + 1.f : expf(y);
    const float zn = Zi[base + t] + Kv;
    sQ[t] = Qv;
    sK[t] = Kv;
    sVv[t] = vv[base + t];
    oZi[base + t] = zn;
    // Z = 1 / (dot(Q, Zi_new) + eps) via wave64 butterfly
    float p = Qv * zn;
    p += __shfl_xor(p, 1);
    p += __shfl_xor(p, 2);
    p += __shfl_xor(p, 4);
    p += __shfl_xor(p, 8);
    p += __shfl_xor(p, 16);
    p += __shfl_xor(p, 32);
    if (t == 0) sZ1 = 1.0f / (p + 1e-6f);
  }
  __syncthreads();

  const f4 val4 = *(const f4*)&sVv[tx * 4];
  f4 acc = (f4)(0.f);

#pragma unroll
  for (int j = 0; j < 4; ++j) {
    const int d = ty + 16 * j;
    const int off = off0 + j * (16 * M);
    const float Kd = sK[d];
    const float Qd = sQ[d];

    f4 u  = Kd * val4;
    f4 pn = (muf * pi[j] - stepf * u) * c1;
    f4 mn = betaf * mi[j] + ombf * (u * u);
    // store pn/mn immediately — no dependence on the rsqrt chain
    __builtin_nontemporal_store(pn, (f4*)&oPi[off]);
    __builtin_nontemporal_store(mn, (f4*)&oMi[off]);

    f4 sn;
    if (use_ri) {
      sn.x = si[j].x - pn.x * ri * rsqrtf(mn.x * inv_bc + 1e-16f);
      sn.y = si[j].y - pn.y * ri * rsqrtf(mn.y * inv_bc + 1e-16f);
      sn.z = si[j].z - pn.z * ri * rsqrtf(mn.z * inv_bc + 1e-16f);
      sn.w = si[j].w - pn.w * ri * rsqrtf(mn.w * inv_bc + 1e-16f);
    } else {
      sn = si[j] - pn;
    }
    __builtin_nontemporal_store(sn, (f4*)&oSi[off]);

    acc += Qd * sn;
  }

  // ---- V reduction: sum over d (16 ty-threads per tx) ----
  acc.x += __shfl_xor(acc.x, 16); acc.x += __shfl_xor(acc.x, 32);
  acc.y += __shfl_xor(acc.y, 16); acc.y += __shfl_xor(acc.y, 32);
  acc.z += __shfl_xor(acc.z, 16); acc.z += __shfl_xor(acc.z, 32);
  acc.w += __shfl_xor(acc.w, 16); acc.w += __shfl_xor(acc.w, 32);

  const int wave = t >> 6;
  const int lane = t & 63;
  if (lane < 16) {
    vred[wave][lane][0] = acc.x;
    vred[wave][lane][1] = acc.y;
    vred[wave][lane][2] = acc.z;
    vred[wave][lane][3] = acc.w;
  }
  __syncthreads();

  if (t < M) {
    const int mtx = t >> 2, mc = t & 3;
    const float s = vred[0][mtx][mc] + vred[1][mtx][mc] +
                    vred[2][mtx][mc] + vred[3][mtx][mc];
    oV[nh * M + t] = sZ1 * s;
  }
}

extern "C" void kernel_launch(void* const* d_in, const int* in_sizes, int n_in,
                              void* d_out, int out_size, void* d_ws, size_t ws_size,
                              hipStream_t stream) {
  const float* q   = (const float*)d_in[0];
  const float* kk  = (const float*)d_in[1];
  const float* vv  = (const float*)d_in[2];
  const float* Si  = (const float*)d_in[3];
  const float* Zi  = (const float*)d_in[4];
  const float* Pi  = (const float*)d_in[5];
  const float* Mi  = (const float*)d_in[6];
  const int*  tind = (const int*)d_in[7];

  // Outputs concatenated in return order: V, Si, Zi, Pi, Mi
  float* out = (float*)d_out;
  float* oV  = out;
  float* oSi = oV  + in_sizes[2];  // V has N*H*M elements (== value size)
  float* oZi = oSi + in_sizes[3];  // Si
  float* oPi = oZi + in_sizes[4];  // Zi
  float* oMi = oPi + in_sizes[5];  // Pi

  const int NH = in_sizes[0] / D;  // 4096
  raa_kernel<<<NH, 256, 0, stream>>>(q, kk, vv, Si, Zi, Pi, Mi, tind,
                                     oV, oSi, oZi, oPi, oMi);
}